// Round 14
// baseline (172.437 us; speedup 1.0000x reference)
//
#include <hip/hip_runtime.h>
#include <hip/hip_bf16.h>

#define NN 20000
#define MM 32
#define EE 20
#define HH 128
#define LOG2E 1.44269504088896f
#define LN2   0.69314718055995f

typedef __attribute__((ext_vector_type(8))) short bf16x8;
typedef __attribute__((ext_vector_type(4))) float f32x4;

// ---------- helpers ----------
__device__ __forceinline__ float bf_lo(unsigned int u) {
    return __uint_as_float(u << 16);
}
__device__ __forceinline__ float bf_hi(unsigned int u) {
    return __uint_as_float(u & 0xFFFF0000u);
}
__device__ __forceinline__ unsigned int pack_bf2(float lo, float hi) {
    unsigned int a = __float_as_uint(lo);
    unsigned int b = __float_as_uint(hi);
    a += 0x7FFFu + ((a >> 16) & 1u);
    b += 0x7FFFu + ((b >> 16) & 1u);
    return (a >> 16) | (b & 0xFFFF0000u);
}
__device__ __forceinline__ unsigned short bf16r(float v) {
    unsigned int u = __float_as_uint(v);
    u += 0x7FFFu + ((u >> 16) & 1u);
    return (unsigned short)(u >> 16);
}
__device__ __forceinline__ float softplusf(float x) {
    return fmaxf(x, 0.f) + __logf(1.f + __expf(-fabsf(x)));
}

// ---------- kernel 1: build Pfrag — MFMA B fragments of proj weights (bf16) ----------
// Pre-scaled by LOG2E.
__global__ void build_pfrag(const float* __restrict__ cheW,
                            const float* __restrict__ vdwW,
                            unsigned short* __restrict__ Pfrag) {
    int t = blockIdx.x * 256 + threadIdx.x;   // < 131072
    int i = t & 7;
    int l = (t >> 3) & 63;
    int ks = (t >> 9) & 3;
    int tile = t >> 11;                       // 0..63
    int j = (tile & 31) * 16 + (l & 15);      // pair col < 512
    int slot = tile >> 5;
    int b = j >> 8, sec = (j >> 7) & 1, h = j & 127;
    int klocal = (l >> 4) * 8 + i;
    int row = (sec ? 256 : 0) + ks * 32 + klocal;
    const float* W = b ? vdwW : cheW;
    Pfrag[t] = bf16r(LOG2E * W[row * 256 + slot * 128 + h]);
}

// ---------- kernel 2: build Bfrag (edge-weight MFMA B fragments) + biasP ----------
// Both pre-scaled by LOG2E.
__global__ void build_bfrag(const float* __restrict__ cheWf, const float* __restrict__ cheBf,
                            const float* __restrict__ cheW,  const float* __restrict__ cheBfull,
                            const float* __restrict__ vdwWf, const float* __restrict__ vdwBf,
                            const float* __restrict__ vdwW,  const float* __restrict__ vdwBfull,
                            unsigned short* __restrict__ Bfrag, float* __restrict__ biasP) {
    int t = blockIdx.x * 256 + threadIdx.x;   // < 2048
    int b = t >> 10, w = (t >> 9) & 1, tc = (t >> 6) & 7, l = t & 63;
    int lhi = l >> 4, llo = l & 15;
    int h = w * 64 + (tc >> 1) * 16 + llo;    // < 128
    int slot = tc & 1;
    int jcol = slot * 128 + h;                // < 256
    const float* Wf = b ? vdwWf : cheWf;
    const float* W  = b ? vdwW  : cheW;

    unsigned short o[8];
#pragma unroll
    for (int i = 0; i < 8; ++i) {
        int k = lhi * 8 + i;
        float a = 0.f;
        if (k < EE)
            for (int h2 = 0; h2 < 128; ++h2)
                a = fmaf(Wf[k * 128 + h2], W[(128 + h2) * 256 + jcol], a);
        o[i] = bf16r(LOG2E * a);
    }
#pragma unroll
    for (int i = 0; i < 8; ++i) Bfrag[t * 8 + i] = o[i];

    if (t < 512) {
        int bb = t >> 8, sl = (t >> 7) & 1, hh = t & 127;
        int jc = sl * 128 + hh;
        const float* bfv   = bb ? vdwBf    : cheBf;
        const float* Wb    = bb ? vdwW     : cheW;
        const float* bfull = bb ? vdwBfull : cheBfull;
        float s = bfull[jc];
        for (int h2 = 0; h2 < 128; ++h2)
            s = fmaf(bfv[h2], Wb[(128 + h2) * 256 + jc], s);
        biasP[t] = LOG2E * s;
    }
}

// ---------- kernel 3: proj GEMM via MFMA — P[n][512]; bias folded into SELF cols ----------
// P column layout (NEW): within [b][sec]: idx = (h&96) | ((h&15)*2) | ((h>>4)&1)
// so a lane's (ht=0, ht=1) pair sits in one aligned uint2.
__global__ __launch_bounds__(256) void proj_mfma(const float* __restrict__ nodes,
                                                 const unsigned short* __restrict__ Pfrag,
                                                 const float* __restrict__ biasP,
                                                 unsigned int* __restrict__ P) {
    __shared__ unsigned short ln[16 * 136];
    int n0 = blockIdx.x * 16;
    int t = threadIdx.x;
    {
        int row = t >> 4, seg = t & 15;
        const float* src = &nodes[(n0 + row) * 128 + seg * 8];
        float4 v0 = *(const float4*)src;
        float4 v1 = *(const float4*)(src + 4);
        uint4 u;
        u.x = pack_bf2(v0.x, v0.y);
        u.y = pack_bf2(v0.z, v0.w);
        u.z = pack_bf2(v1.x, v1.y);
        u.w = pack_bf2(v1.z, v1.w);
        *(uint4*)&ln[row * 136 + seg * 8] = u;
    }
    __syncthreads();

    int w = t >> 6, l = t & 63, lhi = l >> 4, llo = l & 15;
    bf16x8 Af[4];
#pragma unroll
    for (int ks = 0; ks < 4; ++ks)
        Af[ks] = *(const bf16x8*)&ln[llo * 136 + ks * 32 + lhi * 8];

#pragma unroll
    for (int tp = 0; tp < 8; ++tp) {
        int ft = w * 8 + tp;        // filt tile
        int ct = 32 + w * 8 + tp;   // core tile
        f32x4 cf = {0.f, 0.f, 0.f, 0.f};
        f32x4 cc = {0.f, 0.f, 0.f, 0.f};
#pragma unroll
        for (int ks = 0; ks < 4; ++ks) {
            bf16x8 Bf = *(const bf16x8*)&Pfrag[((ft * 4 + ks) * 64 + l) * 8];
            bf16x8 Bc = *(const bf16x8*)&Pfrag[((ct * 4 + ks) * 64 + l) * 8];
            cf = __builtin_amdgcn_mfma_f32_16x16x32_bf16(Af[ks], Bf, cf, 0, 0, 0);
            cc = __builtin_amdgcn_mfma_f32_16x16x32_bf16(Af[ks], Bc, cc, 0, 0, 0);
        }
        int j = w * 128 + tp * 16 + llo;   // logical pair col
        int h = j & 127;
        // ht-interleaved physical column
        int jnew = (j & 0x180) | (h & 96) | ((h & 15) << 1) | ((h >> 4) & 1);
        // fold bias into the SELF section only (sec bit == 0); nbr cols unchanged
        float bF2 = 0.f, bC2 = 0.f;
        if ((j & 128) == 0) {
            int bb = j >> 8, hh = h;
            bF2 = biasP[bb * 256 + hh];
            bC2 = biasP[bb * 256 + 128 + hh];
        }
#pragma unroll
        for (int r = 0; r < 4; ++r)
            P[(size_t)(n0 + lhi * 4 + r) * 512 + jnew] = pack_bf2(cf[r] + bF2, cc[r] + bC2);
    }
}

// ---------- kernel 4: main — uint2 gathers (both ht per load), 8 MFMAs/branch ----------
// one block per node, 256 threads = 4 waves; wave w owns h in [w*32, w*32+32)
__global__ __launch_bounds__(256) void main_kernel(
    const float* __restrict__ nodes,
    const float* __restrict__ rbf_che, const int* __restrict__ idx_che,
    const float* __restrict__ rbf_vdw, const int* __restrict__ idx_vdw,
    const unsigned int* __restrict__ P,
    const unsigned short* __restrict__ Bfrag,
    float* __restrict__ out) {
    __shared__ unsigned short sA[2 * 32 * 40];
    __shared__ int sidx[2][MM];
    int n = blockIdx.x;
    int tid = threadIdx.x;
    int w = tid >> 6, l = tid & 63;       // w in {0..3}
    int lhi = l >> 4, llo = l & 15;
    int wold = w >> 1, whalf = w & 1;

    if (tid < 192) {
        int row = tid / 3, j = tid - row * 3;
        *(uint2*)&sA[row * 40 + 20 + j * 4] = make_uint2(0u, 0u);
    }
    for (int i = tid; i < 320; i += 256) {
        int b = (i >= 160) ? 1 : 0, rem = i - b * 160;
        int m = rem / 5, kq = rem - m * 5;
        const float* src = b ? rbf_vdw : rbf_che;
        float4 v = *(const float4*)&src[n * 640 + m * 20 + kq * 4];
        uint2 p;
        p.x = pack_bf2(v.x, v.y);
        p.y = pack_bf2(v.z, v.w);
        *(uint2*)&sA[(b * 32 + m) * 40 + kq * 4] = p;
    }
    if (tid < 64) {
        int b = tid >> 5, m = tid & 31;
        sidx[b][m] = (b ? idx_vdw : idx_che)[n * MM + m];
    }
    __syncthreads();

    float ps0 = 0.f, ps1 = 0.f;

#pragma unroll
    for (int b = 0; b < 2; ++b) {
        bf16x8 Af0 = *(const bf16x8*)&sA[(b * 32 + llo) * 40 + lhi * 8];
        bf16x8 Af1 = *(const bf16x8*)&sA[(b * 32 + 16 + llo) * 40 + lhi * 8];
        int4 vi0 = *(const int4*)&sidx[b][lhi * 4];
        int4 vi1 = *(const int4*)&sidx[b][16 + lhi * 4];

        int secofs = b * 256 + 128 + w * 32 + llo * 2;   // nbr sec, ht-pair base
        const uint2* gp[8];
        gp[0] = (const uint2*)(P + (size_t)vi0.x * 512 + secofs);
        gp[1] = (const uint2*)(P + (size_t)vi0.y * 512 + secofs);
        gp[2] = (const uint2*)(P + (size_t)vi0.z * 512 + secofs);
        gp[3] = (const uint2*)(P + (size_t)vi0.w * 512 + secofs);
        gp[4] = (const uint2*)(P + (size_t)vi1.x * 512 + secofs);
        gp[5] = (const uint2*)(P + (size_t)vi1.y * 512 + secofs);
        gp[6] = (const uint2*)(P + (size_t)vi1.z * 512 + secofs);
        gp[7] = (const uint2*)(P + (size_t)vi1.w * 512 + secofs);

        const unsigned short* bb = Bfrag + (size_t)((b * 2 + wold) * 8 + whalf * 4) * 512;
        bf16x8 Bff0 = *(const bf16x8*)(bb + (0 * 64 + l) * 8);
        bf16x8 Bfc0 = *(const bf16x8*)(bb + (1 * 64 + l) * 8);
        bf16x8 Bff1 = *(const bf16x8*)(bb + (2 * 64 + l) * 8);
        bf16x8 Bfc1 = *(const bf16x8*)(bb + (3 * 64 + l) * 8);

        uint2 su = *(const uint2*)(P + (size_t)n * 512 + b * 256 + w * 32 + llo * 2);
        float bF0 = bf_lo(su.x), bC0 = bf_hi(su.x);   // bias folded at proj time
        float bF1 = bf_lo(su.y), bC1 = bf_hi(su.y);

        f32x4 f00 = {bF0, bF0, bF0, bF0}, c00 = {bC0, bC0, bC0, bC0};
        f32x4 f01 = {bF1, bF1, bF1, bF1}, c01 = {bC1, bC1, bC1, bC1};
        f32x4 f10 = f00, c10 = c00, f11 = f01, c11 = c01;
        f00 = __builtin_amdgcn_mfma_f32_16x16x32_bf16(Af0, Bff0, f00, 0, 0, 0);
        c00 = __builtin_amdgcn_mfma_f32_16x16x32_bf16(Af0, Bfc0, c00, 0, 0, 0);
        f01 = __builtin_amdgcn_mfma_f32_16x16x32_bf16(Af0, Bff1, f01, 0, 0, 0);
        c01 = __builtin_amdgcn_mfma_f32_16x16x32_bf16(Af0, Bfc1, c01, 0, 0, 0);
        f10 = __builtin_amdgcn_mfma_f32_16x16x32_bf16(Af1, Bff0, f10, 0, 0, 0);
        c10 = __builtin_amdgcn_mfma_f32_16x16x32_bf16(Af1, Bfc0, c10, 0, 0, 0);
        f11 = __builtin_amdgcn_mfma_f32_16x16x32_bf16(Af1, Bff1, f11, 0, 0, 0);
        c11 = __builtin_amdgcn_mfma_f32_16x16x32_bf16(Af1, Bfc1, c11, 0, 0, 0);

        float s0 = 0.f, s1 = 0.f;
        // log2e-scaled: sigmoid = rcp(1+2^-f); softplus/ln2 = log2(1+2^c)
        // core-unpack unmasked: low-16 garbage mantissa <= 2^-17 rel err
#pragma unroll
        for (int r = 0; r < 4; ++r) {
            uint2 g = gp[r][0];
            float fA = f00[r] + bf_lo(g.x);
            float cA = c00[r] + __uint_as_float(g.x);
            s0 = fmaf(__builtin_amdgcn_rcpf(1.f + __builtin_amdgcn_exp2f(-fA)),
                      __builtin_amdgcn_logf(1.f + __builtin_amdgcn_exp2f(cA)), s0);
            float fB = f01[r] + bf_lo(g.y);
            float cB = c01[r] + __uint_as_float(g.y);
            s1 = fmaf(__builtin_amdgcn_rcpf(1.f + __builtin_amdgcn_exp2f(-fB)),
                      __builtin_amdgcn_logf(1.f + __builtin_amdgcn_exp2f(cB)), s1);
        }
#pragma unroll
        for (int r = 0; r < 4; ++r) {
            uint2 g = gp[4 + r][0];
            float fA = f10[r] + bf_lo(g.x);
            float cA = c10[r] + __uint_as_float(g.x);
            s0 = fmaf(__builtin_amdgcn_rcpf(1.f + __builtin_amdgcn_exp2f(-fA)),
                      __builtin_amdgcn_logf(1.f + __builtin_amdgcn_exp2f(cA)), s0);
            float fB = f11[r] + bf_lo(g.y);
            float cB = c11[r] + __uint_as_float(g.y);
            s1 = fmaf(__builtin_amdgcn_rcpf(1.f + __builtin_amdgcn_exp2f(-fB)),
                      __builtin_amdgcn_logf(1.f + __builtin_amdgcn_exp2f(cB)), s1);
        }
        ps0 += s0;
        ps1 += s1;
    }

    float v0 = ps0;
    v0 += __shfl_xor(v0, 16);
    v0 += __shfl_xor(v0, 32);
    float v1 = ps1;
    v1 += __shfl_xor(v1, 16);
    v1 += __shfl_xor(v1, 32);

    if (lhi < 2) {
        int h = w * 32 + lhi * 16 + llo;   // < 128
        float res = lhi ? v1 : v0;
        float x = nodes[n * 128 + h] + LN2 * res;
        out[n * 128 + h] = softplusf(x);
    }
}

// ---------- launch ----------
extern "C" void kernel_launch(void* const* d_in, const int* in_sizes, int n_in,
                              void* d_out, int out_size, void* d_ws, size_t ws_size,
                              hipStream_t stream) {
    const float* nodes     = (const float*)d_in[0];
    const float* che_rbf   = (const float*)d_in[1];
    const int*   che_idx   = (const int*)d_in[2];
    const float* vdw_rbf   = (const float*)d_in[3];
    const int*   vdw_idx   = (const int*)d_in[4];
    const float* che_Wf    = (const float*)d_in[5];
    const float* che_bf    = (const float*)d_in[6];
    const float* che_Wfull = (const float*)d_in[7];
    const float* che_bfull = (const float*)d_in[8];
    const float* vdw_Wf    = (const float*)d_in[9];
    const float* vdw_bf    = (const float*)d_in[10];
    const float* vdw_Wfull = (const float*)d_in[11];
    const float* vdw_bfull = (const float*)d_in[12];

    char* ws = (char*)d_ws;
    unsigned short* Pfrag = (unsigned short*)ws;              // 256 KB
    unsigned short* Bfrag = (unsigned short*)(ws + 262144);   // 32 KB
    float* biasP          = (float*)(ws + 294912);            // 2 KB
    unsigned int* P       = (unsigned int*)(ws + 299008);     // 40.96 MB

    build_pfrag<<<512, 256, 0, stream>>>(che_Wfull, vdw_Wfull, Pfrag);
    build_bfrag<<<8, 256, 0, stream>>>(che_Wf, che_bf, che_Wfull, che_bfull,
                                       vdw_Wf, vdw_bf, vdw_Wfull, vdw_bfull,
                                       Bfrag, biasP);
    proj_mfma<<<NN / 16, 256, 0, stream>>>(nodes, Pfrag, biasP, P);
    main_kernel<<<NN, 256, 0, stream>>>(nodes, che_rbf, che_idx, vdw_rbf, vdw_idx,
                                        P, Bfrag, (float*)d_out);
}

// Round 15
// 167.079 us; speedup vs baseline: 1.0321x; 1.0321x over previous
//
#include <hip/hip_runtime.h>
#include <hip/hip_bf16.h>

#define NN 20000
#define MM 32
#define EE 20
#define HH 128
#define LOG2E 1.44269504088896f
#define LN2   0.69314718055995f

typedef __attribute__((ext_vector_type(8))) short bf16x8;
typedef __attribute__((ext_vector_type(4))) float f32x4;

// ---------- helpers ----------
__device__ __forceinline__ float bf_lo(unsigned int u) {
    return __uint_as_float(u << 16);
}
__device__ __forceinline__ float bf_hi(unsigned int u) {
    return __uint_as_float(u & 0xFFFF0000u);
}
__device__ __forceinline__ unsigned int pack_bf2(float lo, float hi) {
    unsigned int a = __float_as_uint(lo);
    unsigned int b = __float_as_uint(hi);
    a += 0x7FFFu + ((a >> 16) & 1u);
    b += 0x7FFFu + ((b >> 16) & 1u);
    return (a >> 16) | (b & 0xFFFF0000u);
}
__device__ __forceinline__ unsigned short bf16r(float v) {
    unsigned int u = __float_as_uint(v);
    u += 0x7FFFu + ((u >> 16) & 1u);
    return (unsigned short)(u >> 16);
}
__device__ __forceinline__ float softplusf(float x) {
    return fmaxf(x, 0.f) + __logf(1.f + __expf(-fabsf(x)));
}

// ---------- kernel 1: build Pfrag — MFMA B fragments of proj weights (bf16) ----------
// Pre-scaled by LOG2E.
__global__ void build_pfrag(const float* __restrict__ cheW,
                            const float* __restrict__ vdwW,
                            unsigned short* __restrict__ Pfrag) {
    int t = blockIdx.x * 256 + threadIdx.x;   // < 131072
    int i = t & 7;
    int l = (t >> 3) & 63;
    int ks = (t >> 9) & 3;
    int tile = t >> 11;                       // 0..63
    int j = (tile & 31) * 16 + (l & 15);      // pair col < 512
    int slot = tile >> 5;
    int b = j >> 8, sec = (j >> 7) & 1, h = j & 127;
    int klocal = (l >> 4) * 8 + i;
    int row = (sec ? 256 : 0) + ks * 32 + klocal;
    const float* W = b ? vdwW : cheW;
    Pfrag[t] = bf16r(LOG2E * W[row * 256 + slot * 128 + h]);
}

// ---------- kernel 2: build Bfrag (edge-weight MFMA B fragments) + biasP ----------
// Both pre-scaled by LOG2E.
__global__ void build_bfrag(const float* __restrict__ cheWf, const float* __restrict__ cheBf,
                            const float* __restrict__ cheW,  const float* __restrict__ cheBfull,
                            const float* __restrict__ vdwWf, const float* __restrict__ vdwBf,
                            const float* __restrict__ vdwW,  const float* __restrict__ vdwBfull,
                            unsigned short* __restrict__ Bfrag, float* __restrict__ biasP) {
    int t = blockIdx.x * 256 + threadIdx.x;   // < 2048
    int b = t >> 10, w = (t >> 9) & 1, tc = (t >> 6) & 7, l = t & 63;
    int lhi = l >> 4, llo = l & 15;
    int h = w * 64 + (tc >> 1) * 16 + llo;    // < 128
    int slot = tc & 1;
    int jcol = slot * 128 + h;                // < 256
    const float* Wf = b ? vdwWf : cheWf;
    const float* W  = b ? vdwW  : cheW;

    unsigned short o[8];
#pragma unroll
    for (int i = 0; i < 8; ++i) {
        int k = lhi * 8 + i;
        float a = 0.f;
        if (k < EE)
            for (int h2 = 0; h2 < 128; ++h2)
                a = fmaf(Wf[k * 128 + h2], W[(128 + h2) * 256 + jcol], a);
        o[i] = bf16r(LOG2E * a);
    }
#pragma unroll
    for (int i = 0; i < 8; ++i) Bfrag[t * 8 + i] = o[i];

    if (t < 512) {
        int bb = t >> 8, sl = (t >> 7) & 1, hh = t & 127;
        int jc = sl * 128 + hh;
        const float* bfv   = bb ? vdwBf    : cheBf;
        const float* Wb    = bb ? vdwW     : cheW;
        const float* bfull = bb ? vdwBfull : cheBfull;
        float s = bfull[jc];
        for (int h2 = 0; h2 < 128; ++h2)
            s = fmaf(bfv[h2], Wb[(128 + h2) * 256 + jc], s);
        biasP[t] = LOG2E * s;
    }
}

// ---------- kernel 3: proj GEMM via MFMA — P[n][512]; bias folded into SELF cols ----------
__global__ __launch_bounds__(256) void proj_mfma(const float* __restrict__ nodes,
                                                 const unsigned short* __restrict__ Pfrag,
                                                 const float* __restrict__ biasP,
                                                 unsigned int* __restrict__ P) {
    __shared__ unsigned short ln[16 * 136];
    int n0 = blockIdx.x * 16;
    int t = threadIdx.x;
    {
        int row = t >> 4, seg = t & 15;
        const float* src = &nodes[(n0 + row) * 128 + seg * 8];
        float4 v0 = *(const float4*)src;
        float4 v1 = *(const float4*)(src + 4);
        uint4 u;
        u.x = pack_bf2(v0.x, v0.y);
        u.y = pack_bf2(v0.z, v0.w);
        u.z = pack_bf2(v1.x, v1.y);
        u.w = pack_bf2(v1.z, v1.w);
        *(uint4*)&ln[row * 136 + seg * 8] = u;
    }
    __syncthreads();

    int w = t >> 6, l = t & 63, lhi = l >> 4, llo = l & 15;
    bf16x8 Af[4];
#pragma unroll
    for (int ks = 0; ks < 4; ++ks)
        Af[ks] = *(const bf16x8*)&ln[llo * 136 + ks * 32 + lhi * 8];

#pragma unroll
    for (int tp = 0; tp < 8; ++tp) {
        int ft = w * 8 + tp;        // filt tile
        int ct = 32 + w * 8 + tp;   // core tile
        f32x4 cf = {0.f, 0.f, 0.f, 0.f};
        f32x4 cc = {0.f, 0.f, 0.f, 0.f};
#pragma unroll
        for (int ks = 0; ks < 4; ++ks) {
            bf16x8 Bf = *(const bf16x8*)&Pfrag[((ft * 4 + ks) * 64 + l) * 8];
            bf16x8 Bc = *(const bf16x8*)&Pfrag[((ct * 4 + ks) * 64 + l) * 8];
            cf = __builtin_amdgcn_mfma_f32_16x16x32_bf16(Af[ks], Bf, cf, 0, 0, 0);
            cc = __builtin_amdgcn_mfma_f32_16x16x32_bf16(Af[ks], Bc, cc, 0, 0, 0);
        }
        int j = w * 128 + tp * 16 + llo;   // pair col
        // fold bias into the SELF section only (sec bit == 0); nbr cols unchanged
        float bF2 = 0.f, bC2 = 0.f;
        if ((j & 128) == 0) {
            int bb = j >> 8, hh = j & 127;
            bF2 = biasP[bb * 256 + hh];
            bC2 = biasP[bb * 256 + 128 + hh];
        }
#pragma unroll
        for (int r = 0; r < 4; ++r)
            P[(size_t)(n0 + lhi * 4 + r) * 512 + j] = pack_bf2(cf[r] + bF2, cc[r] + bC2);
    }
}

// ---------- kernel 4: main — R12 structure, 2 nodes per 512-thread block ----------
// waves 0-3 own node n0, waves 4-7 own node n0+1; single shared staging barrier.
// Halves workgroup count (10000) to relieve the CP dispatch-rate occupancy cap.
__global__ __launch_bounds__(512) void main_kernel(
    const float* __restrict__ nodes,
    const float* __restrict__ rbf_che, const int* __restrict__ idx_che,
    const float* __restrict__ rbf_vdw, const int* __restrict__ idx_vdw,
    const unsigned int* __restrict__ P,
    const unsigned short* __restrict__ Bfrag,
    float* __restrict__ out) {
    __shared__ unsigned short sA[2][2 * 32 * 40];   // [node][b*32+m][k40]
    __shared__ int sidx[2][2][MM];                  // [node][b][m]
    int n0 = blockIdx.x * 2;
    int tid = threadIdx.x;
    int wall = tid >> 6;                 // 0..7
    int s = wall >> 2;                   // node sub-block 0/1
    int w = wall & 3;                    // wave within node
    int l = tid & 63;
    int lhi = l >> 4, llo = l & 15;
    int wold = w >> 1, whalf = w & 1;
    int n = n0 + s;

    // zero-fill pad k=20..31: 2 nodes x 192
    if (tid < 384) {
        int s2 = tid / 192, r2 = tid - s2 * 192;
        int row = r2 / 3, j = r2 - row * 3;
        *(uint2*)&sA[s2][row * 40 + 20 + j * 4] = make_uint2(0u, 0u);
    }
    // rbf staging: 2 nodes x 320 float4
    for (int i = tid; i < 640; i += 512) {
        int s2 = i >= 320 ? 1 : 0, rem = i - s2 * 320;
        int b = rem >= 160 ? 1 : 0, r2 = rem - b * 160;
        int m = r2 / 5, kq = r2 - m * 5;
        const float* src = b ? rbf_vdw : rbf_che;
        float4 v = *(const float4*)&src[(n0 + s2) * 640 + m * 20 + kq * 4];
        uint2 p;
        p.x = pack_bf2(v.x, v.y);
        p.y = pack_bf2(v.z, v.w);
        *(uint2*)&sA[s2][(b * 32 + m) * 40 + kq * 4] = p;
    }
    if (tid < 128) {
        int s2 = tid >> 6, t2 = tid & 63;
        int b = t2 >> 5, m = t2 & 31;
        sidx[s2][b][m] = (b ? idx_vdw : idx_che)[(n0 + s2) * MM + m];
    }
    __syncthreads();

    float ps0 = 0.f, ps1 = 0.f;

#pragma unroll
    for (int b = 0; b < 2; ++b) {
        bf16x8 Af0 = *(const bf16x8*)&sA[s][(b * 32 + llo) * 40 + lhi * 8];
        bf16x8 Af1 = *(const bf16x8*)&sA[s][(b * 32 + 16 + llo) * 40 + lhi * 8];
        int4 vi0 = *(const int4*)&sidx[s][b][lhi * 4];
        int4 vi1 = *(const int4*)&sidx[s][b][16 + lhi * 4];

        int secofs = b * 256 + 128 + w * 32 + llo;
        const unsigned int* gp[8];
        gp[0] = P + (size_t)vi0.x * 512 + secofs;
        gp[1] = P + (size_t)vi0.y * 512 + secofs;
        gp[2] = P + (size_t)vi0.z * 512 + secofs;
        gp[3] = P + (size_t)vi0.w * 512 + secofs;
        gp[4] = P + (size_t)vi1.x * 512 + secofs;
        gp[5] = P + (size_t)vi1.y * 512 + secofs;
        gp[6] = P + (size_t)vi1.z * 512 + secofs;
        gp[7] = P + (size_t)vi1.w * 512 + secofs;

        const unsigned int* sp = P + (size_t)n * 512 + b * 256 + w * 32 + llo;
        const unsigned short* bb = Bfrag + (size_t)((b * 2 + wold) * 8 + whalf * 4) * 512;

#pragma unroll
        for (int ht = 0; ht < 2; ++ht) {
            bf16x8 Bff = *(const bf16x8*)(bb + ((ht * 2) * 64 + l) * 8);
            bf16x8 Bfc = *(const bf16x8*)(bb + ((ht * 2 + 1) * 64 + l) * 8);

            unsigned int su = sp[ht * 16];      // bias already folded in
            float baseF = bf_lo(su);
            float baseC = bf_hi(su);

            f32x4 a0f = {baseF, baseF, baseF, baseF};
            f32x4 a0c = {baseC, baseC, baseC, baseC};
            f32x4 a1f = a0f, a1c = a0c;
            a0f = __builtin_amdgcn_mfma_f32_16x16x32_bf16(Af0, Bff, a0f, 0, 0, 0);
            a0c = __builtin_amdgcn_mfma_f32_16x16x32_bf16(Af0, Bfc, a0c, 0, 0, 0);
            a1f = __builtin_amdgcn_mfma_f32_16x16x32_bf16(Af1, Bff, a1f, 0, 0, 0);
            a1c = __builtin_amdgcn_mfma_f32_16x16x32_bf16(Af1, Bfc, a1c, 0, 0, 0);

            float s2 = 0.f;
            // log2e-scaled: sigmoid = rcp(1+2^-f); softplus/ln2 = log2(1+2^c)
            // core-unpack unmasked: low-16 garbage mantissa <= 2^-17 rel err
#pragma unroll
            for (int r = 0; r < 4; ++r) {
                unsigned int g = gp[r][ht * 16];
                float filt = a0f[r] + bf_lo(g);
                float core = a0c[r] + __uint_as_float(g);
                float sg = __builtin_amdgcn_rcpf(1.f + __builtin_amdgcn_exp2f(-filt));
                float sop = __builtin_amdgcn_logf(1.f + __builtin_amdgcn_exp2f(core));
                s2 = fmaf(sg, sop, s2);
            }
#pragma unroll
            for (int r = 0; r < 4; ++r) {
                unsigned int g = gp[4 + r][ht * 16];
                float filt = a1f[r] + bf_lo(g);
                float core = a1c[r] + __uint_as_float(g);
                float sg = __builtin_amdgcn_rcpf(1.f + __builtin_amdgcn_exp2f(-filt));
                float sop = __builtin_amdgcn_logf(1.f + __builtin_amdgcn_exp2f(core));
                s2 = fmaf(sg, sop, s2);
            }
            if (ht == 0) ps0 += s2;
            else ps1 += s2;
        }
    }

    float v0 = ps0;
    v0 += __shfl_xor(v0, 16);
    v0 += __shfl_xor(v0, 32);
    float v1 = ps1;
    v1 += __shfl_xor(v1, 16);
    v1 += __shfl_xor(v1, 32);

    if (lhi < 2) {
        int h = w * 32 + lhi * 16 + llo;   // < 128
        float res = lhi ? v1 : v0;
        float x = nodes[n * 128 + h] + LN2 * res;
        out[n * 128 + h] = softplusf(x);
    }
}

// ---------- launch ----------
extern "C" void kernel_launch(void* const* d_in, const int* in_sizes, int n_in,
                              void* d_out, int out_size, void* d_ws, size_t ws_size,
                              hipStream_t stream) {
    const float* nodes     = (const float*)d_in[0];
    const float* che_rbf   = (const float*)d_in[1];
    const int*   che_idx   = (const int*)d_in[2];
    const float* vdw_rbf   = (const float*)d_in[3];
    const int*   vdw_idx   = (const int*)d_in[4];
    const float* che_Wf    = (const float*)d_in[5];
    const float* che_bf    = (const float*)d_in[6];
    const float* che_Wfull = (const float*)d_in[7];
    const float* che_bfull = (const float*)d_in[8];
    const float* vdw_Wf    = (const float*)d_in[9];
    const float* vdw_bf    = (const float*)d_in[10];
    const float* vdw_Wfull = (const float*)d_in[11];
    const float* vdw_bfull = (const float*)d_in[12];

    char* ws = (char*)d_ws;
    unsigned short* Pfrag = (unsigned short*)ws;              // 256 KB
    unsigned short* Bfrag = (unsigned short*)(ws + 262144);   // 32 KB
    float* biasP          = (float*)(ws + 294912);            // 2 KB
    unsigned int* P       = (unsigned int*)(ws + 299008);     // 40.96 MB

    build_pfrag<<<512, 256, 0, stream>>>(che_Wfull, vdw_Wfull, Pfrag);
    build_bfrag<<<8, 256, 0, stream>>>(che_Wf, che_bf, che_Wfull, che_bfull,
                                       vdw_Wf, vdw_bf, vdw_Wfull, vdw_bfull,
                                       Bfrag, biasP);
    proj_mfma<<<NN / 16, 256, 0, stream>>>(nodes, Pfrag, biasP, P);
    main_kernel<<<NN / 2, 512, 0, stream>>>(nodes, che_rbf, che_idx, vdw_rbf, vdw_idx,
                                            P, Bfrag, (float*)d_out);
}

// Round 16
// 164.179 us; speedup vs baseline: 1.0503x; 1.0177x over previous
//
#include <hip/hip_runtime.h>
#include <hip/hip_bf16.h>

#define NN 20000
#define MM 32
#define EE 20
#define HH 128
#define LOG2E 1.44269504088896f
#define LN2   0.69314718055995f

typedef __attribute__((ext_vector_type(8))) short bf16x8;
typedef __attribute__((ext_vector_type(4))) float f32x4;

// ---------- helpers ----------
__device__ __forceinline__ float bf_lo(unsigned int u) {
    return __uint_as_float(u << 16);
}
__device__ __forceinline__ float bf_hi(unsigned int u) {
    return __uint_as_float(u & 0xFFFF0000u);
}
__device__ __forceinline__ unsigned int pack_bf2(float lo, float hi) {
    unsigned int a = __float_as_uint(lo);
    unsigned int b = __float_as_uint(hi);
    a += 0x7FFFu + ((a >> 16) & 1u);
    b += 0x7FFFu + ((b >> 16) & 1u);
    return (a >> 16) | (b & 0xFFFF0000u);
}
__device__ __forceinline__ unsigned short bf16r(float v) {
    unsigned int u = __float_as_uint(v);
    u += 0x7FFFu + ((u >> 16) & 1u);
    return (unsigned short)(u >> 16);
}
__device__ __forceinline__ float softplusf(float x) {
    return fmaxf(x, 0.f) + __logf(1.f + __expf(-fabsf(x)));
}

// ---------- kernel 1: build Pfrag — MFMA B fragments of proj weights (bf16) ----------
// Pre-scaled by LOG2E.
__global__ void build_pfrag(const float* __restrict__ cheW,
                            const float* __restrict__ vdwW,
                            unsigned short* __restrict__ Pfrag) {
    int t = blockIdx.x * 256 + threadIdx.x;   // < 131072
    int i = t & 7;
    int l = (t >> 3) & 63;
    int ks = (t >> 9) & 3;
    int tile = t >> 11;                       // 0..63
    int j = (tile & 31) * 16 + (l & 15);      // pair col < 512
    int slot = tile >> 5;
    int b = j >> 8, sec = (j >> 7) & 1, h = j & 127;
    int klocal = (l >> 4) * 8 + i;
    int row = (sec ? 256 : 0) + ks * 32 + klocal;
    const float* W = b ? vdwW : cheW;
    Pfrag[t] = bf16r(LOG2E * W[row * 256 + slot * 128 + h]);
}

// ---------- kernel 2: build Bfrag (edge-weight MFMA B fragments) + biasP ----------
// Both pre-scaled by LOG2E.
__global__ void build_bfrag(const float* __restrict__ cheWf, const float* __restrict__ cheBf,
                            const float* __restrict__ cheW,  const float* __restrict__ cheBfull,
                            const float* __restrict__ vdwWf, const float* __restrict__ vdwBf,
                            const float* __restrict__ vdwW,  const float* __restrict__ vdwBfull,
                            unsigned short* __restrict__ Bfrag, float* __restrict__ biasP) {
    int t = blockIdx.x * 256 + threadIdx.x;   // < 2048
    int b = t >> 10, w = (t >> 9) & 1, tc = (t >> 6) & 7, l = t & 63;
    int lhi = l >> 4, llo = l & 15;
    int h = w * 64 + (tc >> 1) * 16 + llo;    // < 128
    int slot = tc & 1;
    int jcol = slot * 128 + h;                // < 256
    const float* Wf = b ? vdwWf : cheWf;
    const float* W  = b ? vdwW  : cheW;

    unsigned short o[8];
#pragma unroll
    for (int i = 0; i < 8; ++i) {
        int k = lhi * 8 + i;
        float a = 0.f;
        if (k < EE)
            for (int h2 = 0; h2 < 128; ++h2)
                a = fmaf(Wf[k * 128 + h2], W[(128 + h2) * 256 + jcol], a);
        o[i] = bf16r(LOG2E * a);
    }
#pragma unroll
    for (int i = 0; i < 8; ++i) Bfrag[t * 8 + i] = o[i];

    if (t < 512) {
        int bb = t >> 8, sl = (t >> 7) & 1, hh = t & 127;
        int jc = sl * 128 + hh;
        const float* bfv   = bb ? vdwBf    : cheBf;
        const float* Wb    = bb ? vdwW     : cheW;
        const float* bfull = bb ? vdwBfull : cheBfull;
        float s = bfull[jc];
        for (int h2 = 0; h2 < 128; ++h2)
            s = fmaf(bfv[h2], Wb[(128 + h2) * 256 + jc], s);
        biasP[t] = LOG2E * s;
    }
}

// ---------- kernel 3: proj GEMM via MFMA — P[n][512]; bias folded into SELF cols ----------
__global__ __launch_bounds__(256) void proj_mfma(const float* __restrict__ nodes,
                                                 const unsigned short* __restrict__ Pfrag,
                                                 const float* __restrict__ biasP,
                                                 unsigned int* __restrict__ P) {
    __shared__ unsigned short ln[16 * 136];
    int n0 = blockIdx.x * 16;
    int t = threadIdx.x;
    {
        int row = t >> 4, seg = t & 15;
        const float* src = &nodes[(n0 + row) * 128 + seg * 8];
        float4 v0 = *(const float4*)src;
        float4 v1 = *(const float4*)(src + 4);
        uint4 u;
        u.x = pack_bf2(v0.x, v0.y);
        u.y = pack_bf2(v0.z, v0.w);
        u.z = pack_bf2(v1.x, v1.y);
        u.w = pack_bf2(v1.z, v1.w);
        *(uint4*)&ln[row * 136 + seg * 8] = u;
    }
    __syncthreads();

    int w = t >> 6, l = t & 63, lhi = l >> 4, llo = l & 15;
    bf16x8 Af[4];
#pragma unroll
    for (int ks = 0; ks < 4; ++ks)
        Af[ks] = *(const bf16x8*)&ln[llo * 136 + ks * 32 + lhi * 8];

#pragma unroll
    for (int tp = 0; tp < 8; ++tp) {
        int ft = w * 8 + tp;        // filt tile
        int ct = 32 + w * 8 + tp;   // core tile
        f32x4 cf = {0.f, 0.f, 0.f, 0.f};
        f32x4 cc = {0.f, 0.f, 0.f, 0.f};
#pragma unroll
        for (int ks = 0; ks < 4; ++ks) {
            bf16x8 Bf = *(const bf16x8*)&Pfrag[((ft * 4 + ks) * 64 + l) * 8];
            bf16x8 Bc = *(const bf16x8*)&Pfrag[((ct * 4 + ks) * 64 + l) * 8];
            cf = __builtin_amdgcn_mfma_f32_16x16x32_bf16(Af[ks], Bf, cf, 0, 0, 0);
            cc = __builtin_amdgcn_mfma_f32_16x16x32_bf16(Af[ks], Bc, cc, 0, 0, 0);
        }
        int j = w * 128 + tp * 16 + llo;   // pair col
        // fold bias into the SELF section only (sec bit == 0); nbr cols unchanged
        float bF2 = 0.f, bC2 = 0.f;
        if ((j & 128) == 0) {
            int bb = j >> 8, hh = j & 127;
            bF2 = biasP[bb * 256 + hh];
            bC2 = biasP[bb * 256 + 128 + hh];
        }
#pragma unroll
        for (int r = 0; r < 4; ++r)
            P[(size_t)(n0 + lhi * 4 + r) * 512 + j] = pack_bf2(cf[r] + bF2, cc[r] + bC2);
    }
}

// ---------- kernel 4: main — R15 structure + 32-bit gather addressing ----------
// waves 0-3 own node n0, waves 4-7 own node n0+1; single shared staging barrier.
// Gathers use unsigned byte offsets off the P base (table is 41 MB < 4 GB) so the
// compiler can emit saddr-form global_load (64b SGPR base + 32b VGPR offset).
__global__ __launch_bounds__(512) void main_kernel(
    const float* __restrict__ nodes,
    const float* __restrict__ rbf_che, const int* __restrict__ idx_che,
    const float* __restrict__ rbf_vdw, const int* __restrict__ idx_vdw,
    const unsigned int* __restrict__ P,
    const unsigned short* __restrict__ Bfrag,
    float* __restrict__ out) {
    __shared__ unsigned short sA[2][2 * 32 * 40];   // [node][b*32+m][k40]
    __shared__ int sidx[2][2][MM];                  // [node][b][m]
    int n0 = blockIdx.x * 2;
    int tid = threadIdx.x;
    int wall = tid >> 6;                 // 0..7
    int s = wall >> 2;                   // node sub-block 0/1
    int w = wall & 3;                    // wave within node
    int l = tid & 63;
    int lhi = l >> 4, llo = l & 15;
    int wold = w >> 1, whalf = w & 1;
    int n = n0 + s;

    const char* Pb = (const char*)P;

    // zero-fill pad k=20..31: 2 nodes x 192
    if (tid < 384) {
        int s2 = tid / 192, r2 = tid - s2 * 192;
        int row = r2 / 3, j = r2 - row * 3;
        *(uint2*)&sA[s2][row * 40 + 20 + j * 4] = make_uint2(0u, 0u);
    }
    // rbf staging: 2 nodes x 320 float4
    for (int i = tid; i < 640; i += 512) {
        int s2 = i >= 320 ? 1 : 0, rem = i - s2 * 320;
        int b = rem >= 160 ? 1 : 0, r2 = rem - b * 160;
        int m = r2 / 5, kq = r2 - m * 5;
        const float* src = b ? rbf_vdw : rbf_che;
        float4 v = *(const float4*)&src[(n0 + s2) * 640 + m * 20 + kq * 4];
        uint2 p;
        p.x = pack_bf2(v.x, v.y);
        p.y = pack_bf2(v.z, v.w);
        *(uint2*)&sA[s2][(b * 32 + m) * 40 + kq * 4] = p;
    }
    if (tid < 128) {
        int s2 = tid >> 6, t2 = tid & 63;
        int b = t2 >> 5, m = t2 & 31;
        sidx[s2][b][m] = (b ? idx_vdw : idx_che)[(n0 + s2) * MM + m];
    }
    __syncthreads();

    float ps0 = 0.f, ps1 = 0.f;

#pragma unroll
    for (int b = 0; b < 2; ++b) {
        bf16x8 Af0 = *(const bf16x8*)&sA[s][(b * 32 + llo) * 40 + lhi * 8];
        bf16x8 Af1 = *(const bf16x8*)&sA[s][(b * 32 + 16 + llo) * 40 + lhi * 8];
        int4 vi0 = *(const int4*)&sidx[s][b][lhi * 4];
        int4 vi1 = *(const int4*)&sidx[s][b][16 + lhi * 4];

        // 32-bit byte offsets: row = idx*2048 B, col = (b*256+128+w*32+llo)*4 B
        unsigned secofs = (unsigned)(b * 256 + 128 + w * 32 + llo) * 4u;
        unsigned go[8];
        go[0] = (unsigned)vi0.x * 2048u + secofs;
        go[1] = (unsigned)vi0.y * 2048u + secofs;
        go[2] = (unsigned)vi0.z * 2048u + secofs;
        go[3] = (unsigned)vi0.w * 2048u + secofs;
        go[4] = (unsigned)vi1.x * 2048u + secofs;
        go[5] = (unsigned)vi1.y * 2048u + secofs;
        go[6] = (unsigned)vi1.z * 2048u + secofs;
        go[7] = (unsigned)vi1.w * 2048u + secofs;

        unsigned so = (unsigned)n * 2048u + (unsigned)(b * 256 + w * 32 + llo) * 4u;
        const unsigned short* bb = Bfrag + (size_t)((b * 2 + wold) * 8 + whalf * 4) * 512;

#pragma unroll
        for (int ht = 0; ht < 2; ++ht) {
            bf16x8 Bff = *(const bf16x8*)(bb + ((ht * 2) * 64 + l) * 8);
            bf16x8 Bfc = *(const bf16x8*)(bb + ((ht * 2 + 1) * 64 + l) * 8);

            unsigned int su = *(const unsigned int*)(Pb + so + ht * 64);  // bias folded
            float baseF = bf_lo(su);
            float baseC = bf_hi(su);

            f32x4 a0f = {baseF, baseF, baseF, baseF};
            f32x4 a0c = {baseC, baseC, baseC, baseC};
            f32x4 a1f = a0f, a1c = a0c;
            a0f = __builtin_amdgcn_mfma_f32_16x16x32_bf16(Af0, Bff, a0f, 0, 0, 0);
            a0c = __builtin_amdgcn_mfma_f32_16x16x32_bf16(Af0, Bfc, a0c, 0, 0, 0);
            a1f = __builtin_amdgcn_mfma_f32_16x16x32_bf16(Af1, Bff, a1f, 0, 0, 0);
            a1c = __builtin_amdgcn_mfma_f32_16x16x32_bf16(Af1, Bfc, a1c, 0, 0, 0);

            float s2 = 0.f;
            // log2e-scaled: sigmoid = rcp(1+2^-f); softplus/ln2 = log2(1+2^c)
            // core-unpack unmasked: low-16 garbage mantissa <= 2^-17 rel err
#pragma unroll
            for (int r = 0; r < 4; ++r) {
                unsigned int g = *(const unsigned int*)(Pb + go[r] + ht * 64);
                float filt = a0f[r] + bf_lo(g);
                float core = a0c[r] + __uint_as_float(g);
                float sg = __builtin_amdgcn_rcpf(1.f + __builtin_amdgcn_exp2f(-filt));
                float sop = __builtin_amdgcn_logf(1.f + __builtin_amdgcn_exp2f(core));
                s2 = fmaf(sg, sop, s2);
            }
#pragma unroll
            for (int r = 0; r < 4; ++r) {
                unsigned int g = *(const unsigned int*)(Pb + go[4 + r] + ht * 64);
                float filt = a1f[r] + bf_lo(g);
                float core = a1c[r] + __uint_as_float(g);
                float sg = __builtin_amdgcn_rcpf(1.f + __builtin_amdgcn_exp2f(-filt));
                float sop = __builtin_amdgcn_logf(1.f + __builtin_amdgcn_exp2f(core));
                s2 = fmaf(sg, sop, s2);
            }
            if (ht == 0) ps0 += s2;
            else ps1 += s2;
        }
    }

    float v0 = ps0;
    v0 += __shfl_xor(v0, 16);
    v0 += __shfl_xor(v0, 32);
    float v1 = ps1;
    v1 += __shfl_xor(v1, 16);
    v1 += __shfl_xor(v1, 32);

    if (lhi < 2) {
        int h = w * 32 + lhi * 16 + llo;   // < 128
        float res = lhi ? v1 : v0;
        float x = nodes[n * 128 + h] + LN2 * res;
        out[n * 128 + h] = softplusf(x);
    }
}

// ---------- launch ----------
extern "C" void kernel_launch(void* const* d_in, const int* in_sizes, int n_in,
                              void* d_out, int out_size, void* d_ws, size_t ws_size,
                              hipStream_t stream) {
    const float* nodes     = (const float*)d_in[0];
    const float* che_rbf   = (const float*)d_in[1];
    const int*   che_idx   = (const int*)d_in[2];
    const float* vdw_rbf   = (const float*)d_in[3];
    const int*   vdw_idx   = (const int*)d_in[4];
    const float* che_Wf    = (const float*)d_in[5];
    const float* che_bf    = (const float*)d_in[6];
    const float* che_Wfull = (const float*)d_in[7];
    const float* che_bfull = (const float*)d_in[8];
    const float* vdw_Wf    = (const float*)d_in[9];
    const float* vdw_bf    = (const float*)d_in[10];
    const float* vdw_Wfull = (const float*)d_in[11];
    const float* vdw_bfull = (const float*)d_in[12];

    char* ws = (char*)d_ws;
    unsigned short* Pfrag = (unsigned short*)ws;              // 256 KB
    unsigned short* Bfrag = (unsigned short*)(ws + 262144);   // 32 KB
    float* biasP          = (float*)(ws + 294912);            // 2 KB
    unsigned int* P       = (unsigned int*)(ws + 299008);     // 40.96 MB

    build_pfrag<<<512, 256, 0, stream>>>(che_Wfull, vdw_Wfull, Pfrag);
    build_bfrag<<<8, 256, 0, stream>>>(che_Wf, che_bf, che_Wfull, che_bfull,
                                       vdw_Wf, vdw_bf, vdw_Wfull, vdw_bfull,
                                       Bfrag, biasP);
    proj_mfma<<<NN / 16, 256, 0, stream>>>(nodes, Pfrag, biasP, P);
    main_kernel<<<NN / 2, 512, 0, stream>>>(nodes, che_rbf, che_idx, vdw_rbf, vdw_idx,
                                            P, Bfrag, (float*)d_out);
}

// Round 17
// 161.188 us; speedup vs baseline: 1.0698x; 1.0186x over previous
//
#include <hip/hip_runtime.h>
#include <hip/hip_bf16.h>

#define NN 20000
#define MM 32
#define EE 20
#define HH 128
#define LOG2E 1.44269504088896f
#define LN2   0.69314718055995f

typedef __attribute__((ext_vector_type(8))) short bf16x8;
typedef __attribute__((ext_vector_type(4))) float f32x4;

// ---------- helpers ----------
__device__ __forceinline__ float bf_lo(unsigned int u) {
    return __uint_as_float(u << 16);
}
__device__ __forceinline__ float bf_hi(unsigned int u) {
    return __uint_as_float(u & 0xFFFF0000u);
}
__device__ __forceinline__ unsigned int pack_bf2(float lo, float hi) {
    unsigned int a = __float_as_uint(lo);
    unsigned int b = __float_as_uint(hi);
    a += 0x7FFFu + ((a >> 16) & 1u);
    b += 0x7FFFu + ((b >> 16) & 1u);
    return (a >> 16) | (b & 0xFFFF0000u);
}
__device__ __forceinline__ unsigned short bf16r(float v) {
    unsigned int u = __float_as_uint(v);
    u += 0x7FFFu + ((u >> 16) & 1u);
    return (unsigned short)(u >> 16);
}
__device__ __forceinline__ float softplusf(float x) {
    return fmaxf(x, 0.f) + __logf(1.f + __expf(-fabsf(x)));
}
// gate pair: sigmoid(filt') * softplus(core')/ln2, log2e-scaled domain
__device__ __forceinline__ float gatepair(float a, float c, unsigned g, float s) {
    float filt = a + bf_lo(g);
    float core = c + __uint_as_float(g);   // low-16 garbage <= 2^-17 rel err
    float sg = __builtin_amdgcn_rcpf(1.f + __builtin_amdgcn_exp2f(-filt));
    float sop = __builtin_amdgcn_logf(1.f + __builtin_amdgcn_exp2f(core));
    return fmaf(sg, sop, s);
}

// ---------- kernel 1: merged table build — Pfrag (blocks 0-511), Bfrag+biasP (512-519) ----------
__global__ void build_all(const float* __restrict__ cheWf, const float* __restrict__ cheBf,
                          const float* __restrict__ cheW,  const float* __restrict__ cheBfull,
                          const float* __restrict__ vdwWf, const float* __restrict__ vdwBf,
                          const float* __restrict__ vdwW,  const float* __restrict__ vdwBfull,
                          unsigned short* __restrict__ Pfrag,
                          unsigned short* __restrict__ Bfrag, float* __restrict__ biasP) {
    if (blockIdx.x < 512) {
        int t = blockIdx.x * 256 + threadIdx.x;   // < 131072
        int i = t & 7;
        int l = (t >> 3) & 63;
        int ks = (t >> 9) & 3;
        int tile = t >> 11;                       // 0..63
        int j = (tile & 31) * 16 + (l & 15);      // pair col < 512
        int slot = tile >> 5;
        int b = j >> 8, sec = (j >> 7) & 1, h = j & 127;
        int klocal = (l >> 4) * 8 + i;
        int row = (sec ? 256 : 0) + ks * 32 + klocal;
        const float* W = b ? vdwW : cheW;
        Pfrag[t] = bf16r(LOG2E * W[row * 256 + slot * 128 + h]);
        return;
    }
    int t = (blockIdx.x - 512) * 256 + threadIdx.x;   // < 2048
    int b = t >> 10, w = (t >> 9) & 1, tc = (t >> 6) & 7, l = t & 63;
    int lhi = l >> 4, llo = l & 15;
    int h = w * 64 + (tc >> 1) * 16 + llo;    // < 128
    int slot = tc & 1;
    int jcol = slot * 128 + h;                // < 256
    const float* Wf = b ? vdwWf : cheWf;
    const float* W  = b ? vdwW  : cheW;

    unsigned short o[8];
#pragma unroll
    for (int i = 0; i < 8; ++i) {
        int k = lhi * 8 + i;
        float a = 0.f;
        if (k < EE)
            for (int h2 = 0; h2 < 128; ++h2)
                a = fmaf(Wf[k * 128 + h2], W[(128 + h2) * 256 + jcol], a);
        o[i] = bf16r(LOG2E * a);
    }
#pragma unroll
    for (int i = 0; i < 8; ++i) Bfrag[t * 8 + i] = o[i];

    if (t < 512) {
        int bb = t >> 8, sl = (t >> 7) & 1, hh = t & 127;
        int jc = sl * 128 + hh;
        const float* bfv   = bb ? vdwBf    : cheBf;
        const float* Wb    = bb ? vdwW     : cheW;
        const float* bfull = bb ? vdwBfull : cheBfull;
        float s = bfull[jc];
        for (int h2 = 0; h2 < 128; ++h2)
            s = fmaf(bfv[h2], Wb[(128 + h2) * 256 + jc], s);
        biasP[t] = LOG2E * s;
    }
}

// ---------- kernel 2: proj GEMM via MFMA — P[n][512]; bias folded into SELF cols ----------
__global__ __launch_bounds__(256) void proj_mfma(const float* __restrict__ nodes,
                                                 const unsigned short* __restrict__ Pfrag,
                                                 const float* __restrict__ biasP,
                                                 unsigned int* __restrict__ P) {
    __shared__ unsigned short ln[16 * 136];
    int n0 = blockIdx.x * 16;
    int t = threadIdx.x;
    {
        int row = t >> 4, seg = t & 15;
        const float* src = &nodes[(n0 + row) * 128 + seg * 8];
        float4 v0 = *(const float4*)src;
        float4 v1 = *(const float4*)(src + 4);
        uint4 u;
        u.x = pack_bf2(v0.x, v0.y);
        u.y = pack_bf2(v0.z, v0.w);
        u.z = pack_bf2(v1.x, v1.y);
        u.w = pack_bf2(v1.z, v1.w);
        *(uint4*)&ln[row * 136 + seg * 8] = u;
    }
    __syncthreads();

    int w = t >> 6, l = t & 63, lhi = l >> 4, llo = l & 15;
    bf16x8 Af[4];
#pragma unroll
    for (int ks = 0; ks < 4; ++ks)
        Af[ks] = *(const bf16x8*)&ln[llo * 136 + ks * 32 + lhi * 8];

#pragma unroll
    for (int tp = 0; tp < 8; ++tp) {
        int ft = w * 8 + tp;        // filt tile
        int ct = 32 + w * 8 + tp;   // core tile
        f32x4 cf = {0.f, 0.f, 0.f, 0.f};
        f32x4 cc = {0.f, 0.f, 0.f, 0.f};
#pragma unroll
        for (int ks = 0; ks < 4; ++ks) {
            bf16x8 Bf = *(const bf16x8*)&Pfrag[((ft * 4 + ks) * 64 + l) * 8];
            bf16x8 Bc = *(const bf16x8*)&Pfrag[((ct * 4 + ks) * 64 + l) * 8];
            cf = __builtin_amdgcn_mfma_f32_16x16x32_bf16(Af[ks], Bf, cf, 0, 0, 0);
            cc = __builtin_amdgcn_mfma_f32_16x16x32_bf16(Af[ks], Bc, cc, 0, 0, 0);
        }
        int j = w * 128 + tp * 16 + llo;   // pair col
        float bF2 = 0.f, bC2 = 0.f;
        if ((j & 128) == 0) {
            int bb = j >> 8, hh = j & 127;
            bF2 = biasP[bb * 256 + hh];
            bC2 = biasP[bb * 256 + 128 + hh];
        }
#pragma unroll
        for (int r = 0; r < 4; ++r)
            P[(size_t)(n0 + lhi * 4 + r) * 512 + j] = pack_bf2(cf[r] + bF2, cc[r] + bC2);
    }
}

// ---------- kernel 3: main — R16 + explicit gather hoist above the MFMAs ----------
// waves 0-3 own node n0, waves 4-7 own node n0+1; 32-bit gather addressing.
// All 16 nbr dwords + 2 self dwords named as scalars and issued BEFORE the 8
// MFMAs so their L2/L3 latency hides under the matrix ops (budget: <=64 VGPR
// keeps 8 waves/SIMD).
__global__ __launch_bounds__(512) void main_kernel(
    const float* __restrict__ nodes,
    const float* __restrict__ rbf_che, const int* __restrict__ idx_che,
    const float* __restrict__ rbf_vdw, const int* __restrict__ idx_vdw,
    const unsigned int* __restrict__ P,
    const unsigned short* __restrict__ Bfrag,
    float* __restrict__ out) {
    __shared__ unsigned short sA[2][2 * 32 * 40];   // [node][b*32+m][k40]
    __shared__ int sidx[2][2][MM];                  // [node][b][m]
    int n0 = blockIdx.x * 2;
    int tid = threadIdx.x;
    int wall = tid >> 6;                 // 0..7
    int s = wall >> 2;                   // node sub-block 0/1
    int w = wall & 3;                    // wave within node
    int l = tid & 63;
    int lhi = l >> 4, llo = l & 15;
    int wold = w >> 1, whalf = w & 1;
    int n = n0 + s;

    const char* Pb = (const char*)P;

    if (tid < 384) {
        int s2 = tid / 192, r2 = tid - s2 * 192;
        int row = r2 / 3, j = r2 - row * 3;
        *(uint2*)&sA[s2][row * 40 + 20 + j * 4] = make_uint2(0u, 0u);
    }
    for (int i = tid; i < 640; i += 512) {
        int s2 = i >= 320 ? 1 : 0, rem = i - s2 * 320;
        int b = rem >= 160 ? 1 : 0, r2 = rem - b * 160;
        int m = r2 / 5, kq = r2 - m * 5;
        const float* src = b ? rbf_vdw : rbf_che;
        float4 v = *(const float4*)&src[(n0 + s2) * 640 + m * 20 + kq * 4];
        uint2 p;
        p.x = pack_bf2(v.x, v.y);
        p.y = pack_bf2(v.z, v.w);
        *(uint2*)&sA[s2][(b * 32 + m) * 40 + kq * 4] = p;
    }
    if (tid < 128) {
        int s2 = tid >> 6, t2 = tid & 63;
        int b = t2 >> 5, m = t2 & 31;
        sidx[s2][b][m] = (b ? idx_vdw : idx_che)[(n0 + s2) * MM + m];
    }
    __syncthreads();

    float ps0 = 0.f, ps1 = 0.f;

#pragma unroll
    for (int b = 0; b < 2; ++b) {
        int4 vi0 = *(const int4*)&sidx[s][b][lhi * 4];
        int4 vi1 = *(const int4*)&sidx[s][b][16 + lhi * 4];

        // 32-bit byte offsets
        unsigned secofs = (unsigned)(b * 256 + 128 + w * 32 + llo) * 4u;
        unsigned q0 = (unsigned)vi0.x * 2048u + secofs;
        unsigned q1 = (unsigned)vi0.y * 2048u + secofs;
        unsigned q2 = (unsigned)vi0.z * 2048u + secofs;
        unsigned q3 = (unsigned)vi0.w * 2048u + secofs;
        unsigned q4 = (unsigned)vi1.x * 2048u + secofs;
        unsigned q5 = (unsigned)vi1.y * 2048u + secofs;
        unsigned q6 = (unsigned)vi1.z * 2048u + secofs;
        unsigned q7 = (unsigned)vi1.w * 2048u + secofs;
        unsigned so = (unsigned)n * 2048u + (unsigned)(b * 256 + w * 32 + llo) * 4u;

        // ---- hoisted gather phase: all 18 loads issued before the MFMAs ----
        unsigned gA0 = *(const unsigned*)(Pb + q0);
        unsigned gA1 = *(const unsigned*)(Pb + q1);
        unsigned gA2 = *(const unsigned*)(Pb + q2);
        unsigned gA3 = *(const unsigned*)(Pb + q3);
        unsigned gA4 = *(const unsigned*)(Pb + q4);
        unsigned gA5 = *(const unsigned*)(Pb + q5);
        unsigned gA6 = *(const unsigned*)(Pb + q6);
        unsigned gA7 = *(const unsigned*)(Pb + q7);
        unsigned gB0 = *(const unsigned*)(Pb + q0 + 64);
        unsigned gB1 = *(const unsigned*)(Pb + q1 + 64);
        unsigned gB2 = *(const unsigned*)(Pb + q2 + 64);
        unsigned gB3 = *(const unsigned*)(Pb + q3 + 64);
        unsigned gB4 = *(const unsigned*)(Pb + q4 + 64);
        unsigned gB5 = *(const unsigned*)(Pb + q5 + 64);
        unsigned gB6 = *(const unsigned*)(Pb + q6 + 64);
        unsigned gB7 = *(const unsigned*)(Pb + q7 + 64);
        unsigned su0 = *(const unsigned*)(Pb + so);
        unsigned su1 = *(const unsigned*)(Pb + so + 64);

        // ---- MFMA phase ----
        bf16x8 Af0 = *(const bf16x8*)&sA[s][(b * 32 + llo) * 40 + lhi * 8];
        bf16x8 Af1 = *(const bf16x8*)&sA[s][(b * 32 + 16 + llo) * 40 + lhi * 8];
        const unsigned short* bb = Bfrag + (size_t)((b * 2 + wold) * 8 + whalf * 4) * 512;
        bf16x8 Bff0 = *(const bf16x8*)(bb + (0 * 64 + l) * 8);
        bf16x8 Bfc0 = *(const bf16x8*)(bb + (1 * 64 + l) * 8);
        bf16x8 Bff1 = *(const bf16x8*)(bb + (2 * 64 + l) * 8);
        bf16x8 Bfc1 = *(const bf16x8*)(bb + (3 * 64 + l) * 8);

        float bF0 = bf_lo(su0), bC0 = bf_hi(su0);   // bias folded at proj time
        float bF1 = bf_lo(su1), bC1 = bf_hi(su1);
        f32x4 f00 = {bF0, bF0, bF0, bF0}, c00 = {bC0, bC0, bC0, bC0};
        f32x4 f01 = {bF1, bF1, bF1, bF1}, c01 = {bC1, bC1, bC1, bC1};
        f32x4 f10 = f00, c10 = c00, f11 = f01, c11 = c01;
        f00 = __builtin_amdgcn_mfma_f32_16x16x32_bf16(Af0, Bff0, f00, 0, 0, 0);
        c00 = __builtin_amdgcn_mfma_f32_16x16x32_bf16(Af0, Bfc0, c00, 0, 0, 0);
        f01 = __builtin_amdgcn_mfma_f32_16x16x32_bf16(Af0, Bff1, f01, 0, 0, 0);
        c01 = __builtin_amdgcn_mfma_f32_16x16x32_bf16(Af0, Bfc1, c01, 0, 0, 0);
        f10 = __builtin_amdgcn_mfma_f32_16x16x32_bf16(Af1, Bff0, f10, 0, 0, 0);
        c10 = __builtin_amdgcn_mfma_f32_16x16x32_bf16(Af1, Bfc0, c10, 0, 0, 0);
        f11 = __builtin_amdgcn_mfma_f32_16x16x32_bf16(Af1, Bff1, f11, 0, 0, 0);
        c11 = __builtin_amdgcn_mfma_f32_16x16x32_bf16(Af1, Bfc1, c11, 0, 0, 0);

        // ---- gate epilogue (all operands in registers) ----
        float s0 = 0.f, s1 = 0.f;
        s0 = gatepair(f00[0], c00[0], gA0, s0);
        s0 = gatepair(f00[1], c00[1], gA1, s0);
        s0 = gatepair(f00[2], c00[2], gA2, s0);
        s0 = gatepair(f00[3], c00[3], gA3, s0);
        s0 = gatepair(f10[0], c10[0], gA4, s0);
        s0 = gatepair(f10[1], c10[1], gA5, s0);
        s0 = gatepair(f10[2], c10[2], gA6, s0);
        s0 = gatepair(f10[3], c10[3], gA7, s0);
        s1 = gatepair(f01[0], c01[0], gB0, s1);
        s1 = gatepair(f01[1], c01[1], gB1, s1);
        s1 = gatepair(f01[2], c01[2], gB2, s1);
        s1 = gatepair(f01[3], c01[3], gB3, s1);
        s1 = gatepair(f11[0], c11[0], gB4, s1);
        s1 = gatepair(f11[1], c11[1], gB5, s1);
        s1 = gatepair(f11[2], c11[2], gB6, s1);
        s1 = gatepair(f11[3], c11[3], gB7, s1);
        ps0 += s0;
        ps1 += s1;
    }

    float v0 = ps0;
    v0 += __shfl_xor(v0, 16);
    v0 += __shfl_xor(v0, 32);
    float v1 = ps1;
    v1 += __shfl_xor(v1, 16);
    v1 += __shfl_xor(v1, 32);

    if (lhi < 2) {
        int h = w * 32 + lhi * 16 + llo;   // < 128
        float res = lhi ? v1 : v0;
        float x = nodes[n * 128 + h] + LN2 * res;
        out[n * 128 + h] = softplusf(x);
    }
}

// ---------- launch ----------
extern "C" void kernel_launch(void* const* d_in, const int* in_sizes, int n_in,
                              void* d_out, int out_size, void* d_ws, size_t ws_size,
                              hipStream_t stream) {
    const float* nodes     = (const float*)d_in[0];
    const float* che_rbf   = (const float*)d_in[1];
    const int*   che_idx   = (const int*)d_in[2];
    const float* vdw_rbf   = (const float*)d_in[3];
    const int*   vdw_idx   = (const int*)d_in[4];
    const float* che_Wf    = (const float*)d_in[5];
    const float* che_bf    = (const float*)d_in[6];
    const float* che_Wfull = (const float*)d_in[7];
    const float* che_bfull = (const float*)d_in[8];
    const float* vdw_Wf    = (const float*)d_in[9];
    const float* vdw_bf    = (const float*)d_in[10];
    const float* vdw_Wfull = (const float*)d_in[11];
    const float* vdw_bfull = (const float*)d_in[12];

    char* ws = (char*)d_ws;
    unsigned short* Pfrag = (unsigned short*)ws;              // 256 KB
    unsigned short* Bfrag = (unsigned short*)(ws + 262144);   // 32 KB
    float* biasP          = (float*)(ws + 294912);            // 2 KB
    unsigned int* P       = (unsigned int*)(ws + 299008);     // 40.96 MB

    build_all<<<520, 256, 0, stream>>>(che_Wf, che_bf, che_Wfull, che_bfull,
                                       vdw_Wf, vdw_bf, vdw_Wfull, vdw_bfull,
                                       Pfrag, Bfrag, biasP);
    proj_mfma<<<NN / 16, 256, 0, stream>>>(nodes, Pfrag, biasP, P);
    main_kernel<<<NN / 2, 512, 0, stream>>>(nodes, che_rbf, che_idx, vdw_rbf, vdw_idx,
                                            P, Bfrag, (float*)d_out);
}

// Round 18
// 159.139 us; speedup vs baseline: 1.0836x; 1.0129x over previous
//
#include <hip/hip_runtime.h>
#include <hip/hip_bf16.h>

#define NN 20000
#define MM 32
#define EE 20
#define HH 128
#define LOG2E 1.44269504088896f
#define LN2   0.69314718055995f

typedef __attribute__((ext_vector_type(8))) short bf16x8;
typedef __attribute__((ext_vector_type(4))) float f32x4;

// ---------- helpers ----------
__device__ __forceinline__ float bf_lo(unsigned int u) {
    return __uint_as_float(u << 16);
}
__device__ __forceinline__ float bf_hi(unsigned int u) {
    return __uint_as_float(u & 0xFFFF0000u);
}
__device__ __forceinline__ unsigned int pack_bf2(float lo, float hi) {
    unsigned int a = __float_as_uint(lo);
    unsigned int b = __float_as_uint(hi);
    a += 0x7FFFu + ((a >> 16) & 1u);
    b += 0x7FFFu + ((b >> 16) & 1u);
    return (a >> 16) | (b & 0xFFFF0000u);
}
__device__ __forceinline__ unsigned short bf16r(float v) {
    unsigned int u = __float_as_uint(v);
    u += 0x7FFFu + ((u >> 16) & 1u);
    return (unsigned short)(u >> 16);
}
__device__ __forceinline__ float softplusf(float x) {
    return fmaxf(x, 0.f) + __logf(1.f + __expf(-fabsf(x)));
}

// ---------- kernel 1: merged table build — Pfrag (blocks 0-511), Bfrag+biasP (512-519) ----------
__global__ void build_all(const float* __restrict__ cheWf, const float* __restrict__ cheBf,
                          const float* __restrict__ cheW,  const float* __restrict__ cheBfull,
                          const float* __restrict__ vdwWf, const float* __restrict__ vdwBf,
                          const float* __restrict__ vdwW,  const float* __restrict__ vdwBfull,
                          unsigned short* __restrict__ Pfrag,
                          unsigned short* __restrict__ Bfrag, float* __restrict__ biasP) {
    if (blockIdx.x < 512) {
        int t = blockIdx.x * 256 + threadIdx.x;   // < 131072
        int i = t & 7;
        int l = (t >> 3) & 63;
        int ks = (t >> 9) & 3;
        int tile = t >> 11;                       // 0..63
        int j = (tile & 31) * 16 + (l & 15);      // pair col < 512
        int slot = tile >> 5;
        int b = j >> 8, sec = (j >> 7) & 1, h = j & 127;
        int klocal = (l >> 4) * 8 + i;
        int row = (sec ? 256 : 0) + ks * 32 + klocal;
        const float* W = b ? vdwW : cheW;
        Pfrag[t] = bf16r(LOG2E * W[row * 256 + slot * 128 + h]);
        return;
    }
    int t = (blockIdx.x - 512) * 256 + threadIdx.x;   // < 2048
    int b = t >> 10, w = (t >> 9) & 1, tc = (t >> 6) & 7, l = t & 63;
    int lhi = l >> 4, llo = l & 15;
    int h = w * 64 + (tc >> 1) * 16 + llo;    // < 128
    int slot = tc & 1;
    int jcol = slot * 128 + h;                // < 256
    const float* Wf = b ? vdwWf : cheWf;
    const float* W  = b ? vdwW  : cheW;

    unsigned short o[8];
#pragma unroll
    for (int i = 0; i < 8; ++i) {
        int k = lhi * 8 + i;
        float a = 0.f;
        if (k < EE)
            for (int h2 = 0; h2 < 128; ++h2)
                a = fmaf(Wf[k * 128 + h2], W[(128 + h2) * 256 + jcol], a);
        o[i] = bf16r(LOG2E * a);
    }
#pragma unroll
    for (int i = 0; i < 8; ++i) Bfrag[t * 8 + i] = o[i];

    if (t < 512) {
        int bb = t >> 8, sl = (t >> 7) & 1, hh = t & 127;
        int jc = sl * 128 + hh;
        const float* bfv   = bb ? vdwBf    : cheBf;
        const float* Wb    = bb ? vdwW     : cheW;
        const float* bfull = bb ? vdwBfull : cheBfull;
        float s = bfull[jc];
        for (int h2 = 0; h2 < 128; ++h2)
            s = fmaf(bfv[h2], Wb[(128 + h2) * 256 + jc], s);
        biasP[t] = LOG2E * s;
    }
}

// ---------- kernel 2: proj GEMM via MFMA — P[n][512]; bias folded into SELF cols ----------
__global__ __launch_bounds__(256) void proj_mfma(const float* __restrict__ nodes,
                                                 const unsigned short* __restrict__ Pfrag,
                                                 const float* __restrict__ biasP,
                                                 unsigned int* __restrict__ P) {
    __shared__ unsigned short ln[16 * 136];
    int n0 = blockIdx.x * 16;
    int t = threadIdx.x;
    {
        int row = t >> 4, seg = t & 15;
        const float* src = &nodes[(n0 + row) * 128 + seg * 8];
        float4 v0 = *(const float4*)src;
        float4 v1 = *(const float4*)(src + 4);
        uint4 u;
        u.x = pack_bf2(v0.x, v0.y);
        u.y = pack_bf2(v0.z, v0.w);
        u.z = pack_bf2(v1.x, v1.y);
        u.w = pack_bf2(v1.z, v1.w);
        *(uint4*)&ln[row * 136 + seg * 8] = u;
    }
    __syncthreads();

    int w = t >> 6, l = t & 63, lhi = l >> 4, llo = l & 15;
    bf16x8 Af[4];
#pragma unroll
    for (int ks = 0; ks < 4; ++ks)
        Af[ks] = *(const bf16x8*)&ln[llo * 136 + ks * 32 + lhi * 8];

#pragma unroll
    for (int tp = 0; tp < 8; ++tp) {
        int ft = w * 8 + tp;        // filt tile
        int ct = 32 + w * 8 + tp;   // core tile
        f32x4 cf = {0.f, 0.f, 0.f, 0.f};
        f32x4 cc = {0.f, 0.f, 0.f, 0.f};
#pragma unroll
        for (int ks = 0; ks < 4; ++ks) {
            bf16x8 Bf = *(const bf16x8*)&Pfrag[((ft * 4 + ks) * 64 + l) * 8];
            bf16x8 Bc = *(const bf16x8*)&Pfrag[((ct * 4 + ks) * 64 + l) * 8];
            cf = __builtin_amdgcn_mfma_f32_16x16x32_bf16(Af[ks], Bf, cf, 0, 0, 0);
            cc = __builtin_amdgcn_mfma_f32_16x16x32_bf16(Af[ks], Bc, cc, 0, 0, 0);
        }
        int j = w * 128 + tp * 16 + llo;   // pair col
        // fold bias into the SELF section only (sec bit == 0); nbr cols unchanged
        float bF2 = 0.f, bC2 = 0.f;
        if ((j & 128) == 0) {
            int bb = j >> 8, hh = j & 127;
            bF2 = biasP[bb * 256 + hh];
            bC2 = biasP[bb * 256 + 128 + hh];
        }
#pragma unroll
        for (int r = 0; r < 4; ++r)
            P[(size_t)(n0 + lhi * 4 + r) * 512 + j] = pack_bf2(cf[r] + bF2, cc[r] + bC2);
    }
}

// ---------- kernel 3: main — exact R16 structure (best measured: 124.3 us) ----------
// waves 0-3 own node n0, waves 4-7 own node n0+1; single shared staging barrier.
// 32-bit byte-offset gathers (saddr-form loads); gathers left IN the r-loops —
// R17's explicit hoist cost occupancy (78->66%) and regressed.
__global__ __launch_bounds__(512) void main_kernel(
    const float* __restrict__ nodes,
    const float* __restrict__ rbf_che, const int* __restrict__ idx_che,
    const float* __restrict__ rbf_vdw, const int* __restrict__ idx_vdw,
    const unsigned int* __restrict__ P,
    const unsigned short* __restrict__ Bfrag,
    float* __restrict__ out) {
    __shared__ unsigned short sA[2][2 * 32 * 40];   // [node][b*32+m][k40]
    __shared__ int sidx[2][2][MM];                  // [node][b][m]
    int n0 = blockIdx.x * 2;
    int tid = threadIdx.x;
    int wall = tid >> 6;                 // 0..7
    int s = wall >> 2;                   // node sub-block 0/1
    int w = wall & 3;                    // wave within node
    int l = tid & 63;
    int lhi = l >> 4, llo = l & 15;
    int wold = w >> 1, whalf = w & 1;
    int n = n0 + s;

    const char* Pb = (const char*)P;

    // zero-fill pad k=20..31: 2 nodes x 192
    if (tid < 384) {
        int s2 = tid / 192, r2 = tid - s2 * 192;
        int row = r2 / 3, j = r2 - row * 3;
        *(uint2*)&sA[s2][row * 40 + 20 + j * 4] = make_uint2(0u, 0u);
    }
    // rbf staging: 2 nodes x 320 float4
    for (int i = tid; i < 640; i += 512) {
        int s2 = i >= 320 ? 1 : 0, rem = i - s2 * 320;
        int b = rem >= 160 ? 1 : 0, r2 = rem - b * 160;
        int m = r2 / 5, kq = r2 - m * 5;
        const float* src = b ? rbf_vdw : rbf_che;
        float4 v = *(const float4*)&src[(n0 + s2) * 640 + m * 20 + kq * 4];
        uint2 p;
        p.x = pack_bf2(v.x, v.y);
        p.y = pack_bf2(v.z, v.w);
        *(uint2*)&sA[s2][(b * 32 + m) * 40 + kq * 4] = p;
    }
    if (tid < 128) {
        int s2 = tid >> 6, t2 = tid & 63;
        int b = t2 >> 5, m = t2 & 31;
        sidx[s2][b][m] = (b ? idx_vdw : idx_che)[(n0 + s2) * MM + m];
    }
    __syncthreads();

    float ps0 = 0.f, ps1 = 0.f;

#pragma unroll
    for (int b = 0; b < 2; ++b) {
        bf16x8 Af0 = *(const bf16x8*)&sA[s][(b * 32 + llo) * 40 + lhi * 8];
        bf16x8 Af1 = *(const bf16x8*)&sA[s][(b * 32 + 16 + llo) * 40 + lhi * 8];
        int4 vi0 = *(const int4*)&sidx[s][b][lhi * 4];
        int4 vi1 = *(const int4*)&sidx[s][b][16 + lhi * 4];

        // 32-bit byte offsets: row = idx*2048 B, col = (b*256+128+w*32+llo)*4 B
        unsigned secofs = (unsigned)(b * 256 + 128 + w * 32 + llo) * 4u;
        unsigned go[8];
        go[0] = (unsigned)vi0.x * 2048u + secofs;
        go[1] = (unsigned)vi0.y * 2048u + secofs;
        go[2] = (unsigned)vi0.z * 2048u + secofs;
        go[3] = (unsigned)vi0.w * 2048u + secofs;
        go[4] = (unsigned)vi1.x * 2048u + secofs;
        go[5] = (unsigned)vi1.y * 2048u + secofs;
        go[6] = (unsigned)vi1.z * 2048u + secofs;
        go[7] = (unsigned)vi1.w * 2048u + secofs;

        unsigned so = (unsigned)n * 2048u + (unsigned)(b * 256 + w * 32 + llo) * 4u;
        const unsigned short* bb = Bfrag + (size_t)((b * 2 + wold) * 8 + whalf * 4) * 512;

#pragma unroll
        for (int ht = 0; ht < 2; ++ht) {
            bf16x8 Bff = *(const bf16x8*)(bb + ((ht * 2) * 64 + l) * 8);
            bf16x8 Bfc = *(const bf16x8*)(bb + ((ht * 2 + 1) * 64 + l) * 8);

            unsigned int su = *(const unsigned int*)(Pb + so + ht * 64);  // bias folded
            float baseF = bf_lo(su);
            float baseC = bf_hi(su);

            f32x4 a0f = {baseF, baseF, baseF, baseF};
            f32x4 a0c = {baseC, baseC, baseC, baseC};
            f32x4 a1f = a0f, a1c = a0c;
            a0f = __builtin_amdgcn_mfma_f32_16x16x32_bf16(Af0, Bff, a0f, 0, 0, 0);
            a0c = __builtin_amdgcn_mfma_f32_16x16x32_bf16(Af0, Bfc, a0c, 0, 0, 0);
            a1f = __builtin_amdgcn_mfma_f32_16x16x32_bf16(Af1, Bff, a1f, 0, 0, 0);
            a1c = __builtin_amdgcn_mfma_f32_16x16x32_bf16(Af1, Bfc, a1c, 0, 0, 0);

            float s2 = 0.f;
            // log2e-scaled: sigmoid = rcp(1+2^-f); softplus/ln2 = log2(1+2^c)
            // core-unpack unmasked: low-16 garbage mantissa <= 2^-17 rel err
#pragma unroll
            for (int r = 0; r < 4; ++r) {
                unsigned int g = *(const unsigned int*)(Pb + go[r] + ht * 64);
                float filt = a0f[r] + bf_lo(g);
                float core = a0c[r] + __uint_as_float(g);
                float sg = __builtin_amdgcn_rcpf(1.f + __builtin_amdgcn_exp2f(-filt));
                float sop = __builtin_amdgcn_logf(1.f + __builtin_amdgcn_exp2f(core));
                s2 = fmaf(sg, sop, s2);
            }
#pragma unroll
            for (int r = 0; r < 4; ++r) {
                unsigned int g = *(const unsigned int*)(Pb + go[4 + r] + ht * 64);
                float filt = a1f[r] + bf_lo(g);
                float core = a1c[r] + __uint_as_float(g);
                float sg = __builtin_amdgcn_rcpf(1.f + __builtin_amdgcn_exp2f(-filt));
                float sop = __builtin_amdgcn_logf(1.f + __builtin_amdgcn_exp2f(core));
                s2 = fmaf(sg, sop, s2);
            }
            if (ht == 0) ps0 += s2;
            else ps1 += s2;
        }
    }

    float v0 = ps0;
    v0 += __shfl_xor(v0, 16);
    v0 += __shfl_xor(v0, 32);
    float v1 = ps1;
    v1 += __shfl_xor(v1, 16);
    v1 += __shfl_xor(v1, 32);

    if (lhi < 2) {
        int h = w * 32 + lhi * 16 + llo;   // < 128
        float res = lhi ? v1 : v0;
        float x = nodes[n * 128 + h] + LN2 * res;
        out[n * 128 + h] = softplusf(x);
    }
}

// ---------- launch ----------
extern "C" void kernel_launch(void* const* d_in, const int* in_sizes, int n_in,
                              void* d_out, int out_size, void* d_ws, size_t ws_size,
                              hipStream_t stream) {
    const float* nodes     = (const float*)d_in[0];
    const float* che_rbf   = (const float*)d_in[1];
    const int*   che_idx   = (const int*)d_in[2];
    const float* vdw_rbf   = (const float*)d_in[3];
    const int*   vdw_idx   = (const int*)d_in[4];
    const float* che_Wf    = (const float*)d_in[5];
    const float* che_bf    = (const float*)d_in[6];
    const float* che_Wfull = (const float*)d_in[7];
    const float* che_bfull = (const float*)d_in[8];
    const float* vdw_Wf    = (const float*)d_in[9];
    const float* vdw_bf    = (const float*)d_in[10];
    const float* vdw_Wfull = (const float*)d_in[11];
    const float* vdw_bfull = (const float*)d_in[12];

    char* ws = (char*)d_ws;
    unsigned short* Pfrag = (unsigned short*)ws;              // 256 KB
    unsigned short* Bfrag = (unsigned short*)(ws + 262144);   // 32 KB
    float* biasP          = (float*)(ws + 294912);            // 2 KB
    unsigned int* P       = (unsigned int*)(ws + 299008);     // 40.96 MB

    build_all<<<520, 256, 0, stream>>>(che_Wf, che_bf, che_Wfull, che_bfull,
                                       vdw_Wf, vdw_bf, vdw_Wfull, vdw_bfull,
                                       Pfrag, Bfrag, biasP);
    proj_mfma<<<NN / 16, 256, 0, stream>>>(nodes, Pfrag, biasP, P);
    main_kernel<<<NN / 2, 512, 0, stream>>>(nodes, che_rbf, che_idx, vdw_rbf, vdw_idx,
                                            P, Bfrag, (float*)d_out);
}